// Round 8
// baseline (8791.802 us; speedup 1.0000x reference)
//
#include <hip/hip_runtime.h>

#define SS 4096
#define TT 2048

// clang native vector types: usable directly in asm "v" constraints
typedef float v4f __attribute__((ext_vector_type(4)));
typedef unsigned u2 __attribute__((ext_vector_type(2)));

// ---------- LLC-coherent (agent) memory ops, hand-rolled ----------
// sc0 sc1 => bypass non-coherent per-XCD L2, serve at Infinity Cache.

__device__ __forceinline__ void llc_load4x4(const v4f* p,
                                            v4f& a, v4f& b, v4f& c, v4f& d) {
  asm volatile(
      "global_load_dwordx4 %0, %4, off sc0 sc1\n\t"
      "global_load_dwordx4 %1, %5, off sc0 sc1\n\t"
      "global_load_dwordx4 %2, %6, off sc0 sc1\n\t"
      "global_load_dwordx4 %3, %7, off sc0 sc1\n\t"
      "s_waitcnt vmcnt(0)"
      : "=&v"(a), "=&v"(b), "=&v"(c), "=&v"(d)
      : "v"(p), "v"(p + 256), "v"(p + 512), "v"(p + 768)
      : "memory");
}

// sentinel poll: word 0 of each owned chunk (4B x 4). Each producer chunk is
// written by ONE global_store_dwordx4 (16B, single transaction) -> sentinel
// sign flip implies the whole chunk is LLC-visible.
__device__ __forceinline__ void llc_sent4(const float* p0, const float* p1,
                                          const float* p2, const float* p3,
                                          float& a, float& b, float& c, float& d) {
  asm volatile(
      "global_load_dword %0, %4, off sc0 sc1\n\t"
      "global_load_dword %1, %5, off sc0 sc1\n\t"
      "global_load_dword %2, %6, off sc0 sc1\n\t"
      "global_load_dword %3, %7, off sc0 sc1\n\t"
      "s_waitcnt vmcnt(0)"
      : "=&v"(a), "=&v"(b), "=&v"(c), "=&v"(d)
      : "v"(p0), "v"(p1), "v"(p2), "v"(p3)
      : "memory");
}

// store WITHOUT drain: visibility to peers is unaffected (store is already
// en route to MALL); the producer keeps going. Data VGPRs must stay pinned
// until a later vmcnt(0) — see r_keep discipline in the kernel.
#define LLC_STORE4_NODRAIN(p, v) \
  asm volatile("global_store_dwordx4 %0, %1, off sc0 sc1" \
               :: "v"(p), "v"(v) : "memory")

// raw barrier: lgkmcnt only (LDS visibility), leaves VMEM (emit prefetch,
// q store) in flight — avoids the compiler's vmcnt(0) drain at __syncthreads.
__device__ __forceinline__ void bar_lgkm() {
  asm volatile("s_waitcnt lgkmcnt(0)" ::: "memory");
  __builtin_amdgcn_s_barrier();
}

// ---------- helpers ----------

__device__ __forceinline__ unsigned short f2bf_rn(float f) {
  unsigned int u = __float_as_uint(f);
  u += 0x7FFFu + ((u >> 16) & 1u);   // RNE; inputs positive finite
  return (unsigned short)(u >> 16);
}

__device__ __forceinline__ unsigned pkbf(float a, float b) {
  return (unsigned)f2bf_rn(a) | ((unsigned)f2bf_rn(b) << 16);
}

__device__ __forceinline__ float blo(unsigned w) { return __uint_as_float(w << 16); }
__device__ __forceinline__ float bhi(unsigned w) { return __uint_as_float(w & 0xFFFF0000u); }

// 4 MACs: packed-bf16 E pair-of-pairs vs f32 q vector, f32 accumulate
__device__ __forceinline__ v4f fma4(u2 e, v4f q, v4f a) {
  a.x = fmaf(blo(e.x), q.x, a.x);
  a.y = fmaf(bhi(e.x), q.y, a.y);
  a.z = fmaf(blo(e.y), q.z, a.z);
  a.w = fmaf(bhi(e.y), q.w, a.w);
  return a;
}

// OR of (sign-adjusted) words: ready iff top bit of result is 0
__device__ __forceinline__ unsigned orsgn(v4f v, unsigned e) {
  return (__float_as_uint(v.x) ^ e) | (__float_as_uint(v.y) ^ e)
       | (__float_as_uint(v.z) ^ e) | (__float_as_uint(v.w) ^ e);
}

// ---------- kernel A: q0 = exp(log_M0 + log_emit[0]) (positive = sign for t=0) ----------
__global__ void init_q(const float* __restrict__ m0, const float* __restrict__ emit,
                       float* __restrict__ q) {
  int i = blockIdx.x * 256 + threadIdx.x;
  q[i] = __expf(m0[i] + emit[i]);
}

// ---------- kernel B: persistent forward recursion ----------
// Round-7 skeleton (verified): poll -> stage LDS -> barrier -> GEMV ->
// reduce -> store. Round-8 cuts three self-inflicted round trips that four
// null experiments isolated as the dominant serial term:
//  (1) OWN-CHUNK SPLICE: a block's poll no longer waits for its own
//      store->MALL->load RT; the 4 threads covering the block's own 64B
//      mask it from readiness and splice the value from LDS (qown).
//  (2) NO STORE DRAIN: peers poll; producer proceeds. Data regs pinned
//      via loop-carried r_keep, released after the next poll's vmcnt(0);
//      final drain after the loop.
//  (3) EMIT PREFETCH +1 STEP and RAW BARRIERS (lgkmcnt-only): the emit HBM
//      load no longer sits inside the poll's vmcnt(0), and __syncthreads'
//      compiler-inserted vmcnt(0) drain is avoided.
// Staged values are bit-identical to round 7 (raw, sign folded into scale:
// s_t*s_{t-1} = + odd t, - even t). Stored sign of step t is s_t =
// ((t>>1)&1)? -1:+1; 0xAA poison is negative.
#define K16(X) X(0) X(1) X(2) X(3) X(4) X(5) X(6) X(7) \
               X(8) X(9) X(10) X(11) X(12) X(13) X(14) X(15)

__global__ void __launch_bounds__(256, 1) __attribute__((amdgpu_waves_per_eu(1, 1)))
hmm_fwd(const float* __restrict__ lt, const float* __restrict__ emit,
        float* q, float* out) {
  __shared__ float qs[2][SS];              // 32 KiB (double buffer)
  __shared__ v4f qown[4];                  // own chunk of q_t (raw, signed)
  __shared__ float wsum[4];
  const int b    = blockIdx.x;
  const int tid  = threadIdx.x;
  const int wave = tid >> 6;
  const int lane = tid & 63;
  const int row0 = (b << 4) + (wave << 2);

  // own-chunk geometry: block b's 16 floats live in quarter (b>>6),
  // threads 4*(b&63)..+3, one full v4f each; thread offset == wave index.
  const int  ownth  = tid - ((b & 63) << 2);
  const bool is_own = ((unsigned)ownth) < 4u;
  const int  ownq   = b >> 6;

  // 64 named packed-bf16 E registers:
  // e{r}_{k} = bf16(exp(log_trans[row0+r][k*256+4l .. +4])), 2x2 packed
#define DECL_E(k) u2 e0_##k, e1_##k, e2_##k, e3_##k;
  K16(DECL_E)
#undef DECL_E

  {
    const float* s0 = lt + (size_t)row0 * SS + (lane << 2);
    const float* s1 = s0 + SS;
    const float* s2 = s1 + SS;
    const float* s3 = s2 + SS;
#define INIT_E(k) { \
    v4f t0 = *(const v4f*)(s0 + ((k) << 8)); \
    v4f t1 = *(const v4f*)(s1 + ((k) << 8)); \
    v4f t2 = *(const v4f*)(s2 + ((k) << 8)); \
    v4f t3 = *(const v4f*)(s3 + ((k) << 8)); \
    e0_##k = (u2){pkbf(__expf(t0.x), __expf(t0.y)), pkbf(__expf(t0.z), __expf(t0.w))}; \
    e1_##k = (u2){pkbf(__expf(t1.x), __expf(t1.y)), pkbf(__expf(t1.z), __expf(t1.w))}; \
    e2_##k = (u2){pkbf(__expf(t2.x), __expf(t2.y)), pkbf(__expf(t2.z), __expf(t2.w))}; \
    e3_##k = (u2){pkbf(__expf(t3.x), __expf(t3.y)), pkbf(__expf(t3.z), __expf(t3.w))}; }
    K16(INIT_E)
#undef INIT_E
  }

  // prologue: own chunk of q0 into LDS (init_q completed: kernel order);
  // emit row for t=1 prefetched.
  if (lane == 0) qown[wave] = *(const v4f*)(q + row0);
  v4f em;
  if (lane == 0) em = *(const v4f*)(emit + (size_t)1 * SS + row0);
  v4f r_keep = {0.f, 0.f, 0.f, 0.f};
  __syncthreads();   // one-time full barrier (drains prologue loads too)

  for (int t = 1; t <= TT; ++t) {
    // poll q_{t-1}: expected stored-sign of step t-1 (REMOTE chunks only)
    const unsigned e = (unsigned)(((t - 1) >> 1) & 1) << 31;
    const v4f* qsrc4 = (const v4f*)(q + ((t - 1) & 1) * SS);
    v4f va, vb, vc, vd;
    llc_load4x4(qsrc4 + tid, va, vb, vc, vd);   // vmcnt(0): also drains our
                                                // last store + em prefetch
    asm volatile("" :: "v"(r_keep));            // release store-data pin here
    {
      unsigned o0 = orsgn(va, e), o1 = orsgn(vb, e),
               o2 = orsgn(vc, e), o3 = orsgn(vd, e);
      if (is_own) {   // own chunk: don't wait for our own store's RT
        if      (ownq == 0) o0 = 0;
        else if (ownq == 1) o1 = 0;
        else if (ownq == 2) o2 = 0;
        else                o3 = 0;
      }
      if ((o0 | o1 | o2 | o3) >> 31) {
        // stragglers: cheap 4-dword sentinel spin (16B/thread per pass)
        const float* qw = (const float*)qsrc4;
        const float* p0 = qw + (tid << 2);
        const float* p1 = p0 + 1024;
        const float* p2 = p0 + 2048;
        const float* p3 = p0 + 3072;
        for (;;) {
          float s0v, s1v, s2v, s3v;
          llc_sent4(p0, p1, p2, p3, s0v, s1v, s2v, s3v);
          unsigned w0 = __float_as_uint(s0v) ^ e, w1 = __float_as_uint(s1v) ^ e,
                   w2 = __float_as_uint(s2v) ^ e, w3 = __float_as_uint(s3v) ^ e;
          if (is_own) {
            if      (ownq == 0) w0 = 0;
            else if (ownq == 1) w1 = 0;
            else if (ownq == 2) w2 = 0;
            else                w3 = 0;
          }
          if (!((w0 | w1 | w2 | w3) >> 31)) break;
        }
        llc_load4x4(qsrc4 + tid, va, vb, vc, vd);   // data now LLC-resident
      }
    }
    // own-chunk splice from LDS (value identical to what we stored)
    if (is_own) {
      v4f ov = qown[ownth];
      if      (ownq == 0) va = ov;
      else if (ownq == 1) vb = ov;
      else if (ownq == 2) vc = ov;
      else                vd = ov;
    }
    // stage RAW (sign s_{t-1} kept; folded into output scale)
    {
      v4f* qsb = (v4f*)qs[t & 1];
      qsb[tid]       = va;
      qsb[tid + 256] = vb;
      qsb[tid + 512] = vc;
      qsb[tid + 768] = vd;
    }
    // consume em (prefetched last step, already drained), prefetch next
    v4f ex;
    if (lane == 0) {
      ex.x = __expf(em.x);  ex.y = __expf(em.y);
      ex.z = __expf(em.z);  ex.w = __expf(em.w);
      if (t < TT) em = *(const v4f*)(emit + (size_t)(t + 1) * SS + row0);
    }
    bar_lgkm();   // barrier1: staging visible; em/store stay in flight

    // GEMV: 4 rows per lane from bf16 registers, one v4f of q per k (16 LDS reads)
    v4f a0 = {0.f, 0.f, 0.f, 0.f}, a1 = a0, a2 = a0, a3 = a0;
    const v4f* qv4 = (const v4f*)qs[t & 1];
#define FMA_K(k) { \
    v4f qv = qv4[((k) << 6) + lane]; \
    a0 = fma4(e0_##k, qv, a0);  a1 = fma4(e1_##k, qv, a1); \
    a2 = fma4(e2_##k, qv, a2);  a3 = fma4(e3_##k, qv, a3); }
    K16(FMA_K)
#undef FMA_K

    float acc0 = (a0.x + a0.y) + (a0.z + a0.w);
    float acc1 = (a1.x + a1.y) + (a1.z + a1.w);
    float acc2 = (a2.x + a2.y) + (a2.z + a2.w);
    float acc3 = (a3.x + a3.y) + (a3.z + a3.w);
#pragma unroll
    for (int m = 32; m > 0; m >>= 1) {
      acc0 += __shfl_xor(acc0, m);
      acc1 += __shfl_xor(acc1, m);
      acc2 += __shfl_xor(acc2, m);
      acc3 += __shfl_xor(acc3, m);
    }

    // publish q_t chunk (global, no drain) + own LDS copy
    if (lane == 0) {
      float scale = ((t & 255) == 0) ? 0x1p-46f : 1.0f;  // exact pow2 renorm
      if (!(t & 1)) scale = -scale;                       // s_t * s_{t-1}
      v4f r;
      r.x = acc0 * (ex.x * scale);
      r.y = acc1 * (ex.y * scale);
      r.z = acc2 * (ex.z * scale);
      r.w = acc3 * (ex.w * scale);
      LLC_STORE4_NODRAIN((v4f*)(q + (t & 1) * SS + row0), r);
      qown[wave] = r;     // LDS copy for next step's own-chunk splice
      r_keep = r;         // pin store-data regs until next poll's vmcnt(0)
    }
    bar_lgkm();   // barrier2: qown visible before any wave's next poll
  }

  // drain: last store's data regs must survive until the store completes
  asm volatile("" :: "v"(r_keep));
  asm volatile("s_waitcnt vmcnt(0)" ::: "memory");

  // final reduction: q_T (t=2048) in buffer 0, stored sign positive
  if (b == 0) {
    const v4f* qf4 = (const v4f*)q;
    v4f va, vb, vc, vd;
    for (;;) {
      llc_load4x4(qf4 + tid, va, vb, vc, vd);
      unsigned o = orsgn(va, 0) | orsgn(vb, 0) | orsgn(vc, 0) | orsgn(vd, 0);
      if (!(o >> 31)) break;
    }
    float s = va.x + va.y + va.z + va.w + vb.x + vb.y + vb.z + vb.w
            + vc.x + vc.y + vc.z + vc.w + vd.x + vd.y + vd.z + vd.w;
#pragma unroll
    for (int m = 32; m > 0; m >>= 1) s += __shfl_xor(s, m);
    if (lane == 0) wsum[wave] = s;
    __syncthreads();
    if (tid == 0) {
      float tot = wsum[0] + wsum[1] + wsum[2] + wsum[3];
      out[0] = logf(tot) + 368.0f * 0.693147180559945f;   // 8 rescales * 46 * ln2
    }
  }
}

// ---------- launch ----------
extern "C" void kernel_launch(void* const* d_in, const int* in_sizes, int n_in,
                              void* d_out, int out_size, void* d_ws, size_t ws_size,
                              hipStream_t stream) {
  const float* log_M0    = (const float*)d_in[0];
  const float* log_trans = (const float*)d_in[1];
  const float* log_emit  = (const float*)d_in[2];
  // d_in[3] = T (fixed 2048, unused)

  float* q   = (float*)d_ws;     // 2 x 16 KiB (poisoned 0xAA = negative)
  float* out = (float*)d_out;

  hipLaunchKernelGGL(init_q, dim3(SS / 256), dim3(256), 0, stream, log_M0, log_emit, q);
  hipLaunchKernelGGL(hmm_fwd, dim3(256), dim3(256), 0, stream, log_trans, log_emit, q, out);
}

// Round 9
// 4722.438 us; speedup vs baseline: 1.8617x; 1.8617x over previous
//
#include <hip/hip_runtime.h>

#define SS 4096
#define TT 2048

// clang native vector types: usable directly in asm "v" constraints
typedef float v4f __attribute__((ext_vector_type(4)));
typedef float v2f __attribute__((ext_vector_type(2)));
typedef unsigned u2 __attribute__((ext_vector_type(2)));

// ---------- LLC-coherent (agent) memory ops, hand-rolled ----------
// sc0 sc1 => bypass non-coherent per-XCD L2, serve at Infinity Cache.

// two v4f, 8KB apart (thread's two poll slices)
__device__ __forceinline__ void llc_load2(const v4f* p, v4f& a, v4f& b) {
  asm volatile(
      "global_load_dwordx4 %0, %2, off sc0 sc1\n\t"
      "global_load_dwordx4 %1, %3, off sc0 sc1\n\t"
      "s_waitcnt vmcnt(0)"
      : "=&v"(a), "=&v"(b)
      : "v"(p), "v"(p + 512)
      : "memory");
}

__device__ __forceinline__ void llc_load4x4(const v4f* p,
                                            v4f& a, v4f& b, v4f& c, v4f& d) {
  asm volatile(
      "global_load_dwordx4 %0, %4, off sc0 sc1\n\t"
      "global_load_dwordx4 %1, %5, off sc0 sc1\n\t"
      "global_load_dwordx4 %2, %6, off sc0 sc1\n\t"
      "global_load_dwordx4 %3, %7, off sc0 sc1\n\t"
      "s_waitcnt vmcnt(0)"
      : "=&v"(a), "=&v"(b), "=&v"(c), "=&v"(d)
      : "v"(p), "v"(p + 256), "v"(p + 512), "v"(p + 768)
      : "memory");
}

// sentinel poll: word 0 of each 8B chunk (4B x 4). Each producer chunk is
// written by ONE global_store_dwordx2 (8B, single transaction) -> sentinel
// sign flip implies the whole chunk is LLC-visible.
__device__ __forceinline__ void llc_sent4(const float* p0, const float* p1,
                                          const float* p2, const float* p3,
                                          float& a, float& b, float& c, float& d) {
  asm volatile(
      "global_load_dword %0, %4, off sc0 sc1\n\t"
      "global_load_dword %1, %5, off sc0 sc1\n\t"
      "global_load_dword %2, %6, off sc0 sc1\n\t"
      "global_load_dword %3, %7, off sc0 sc1\n\t"
      "s_waitcnt vmcnt(0)"
      : "=&v"(a), "=&v"(b), "=&v"(c), "=&v"(d)
      : "v"(p0), "v"(p1), "v"(p2), "v"(p3)
      : "memory");
}

// store + vmcnt(0): the drain is LOAD-BEARING (round-8 lesson): it forces
// the write to the coherency point promptly; removing it delayed visibility
// and regressed 1.7x.
__device__ __forceinline__ void llc_store2_drain(float* p, v2f v) {
  asm volatile("global_store_dwordx2 %0, %1, off sc0 sc1\n\t"
               "s_waitcnt vmcnt(0)"
               :: "v"(p), "v"(v) : "memory");
}

// straggle side-channel: 64-way LDS bank conflict (all lanes -> bank 0).
// SQ_LDS_BANK_CONFLICT += ~63 per wave execution => counts retry passes.
__device__ __forceinline__ void straggle_tick(int lane) {
  float dummy;
  asm volatile("ds_read_b32 %0, %1\n\t"
               "s_waitcnt lgkmcnt(0)"
               : "=v"(dummy) : "v"(lane << 7) : "memory");
  asm volatile("" :: "v"(dummy));
}

// ---------- helpers ----------

__device__ __forceinline__ unsigned short f2bf_rn(float f) {
  unsigned int u = __float_as_uint(f);
  u += 0x7FFFu + ((u >> 16) & 1u);   // RNE; inputs positive finite
  return (unsigned short)(u >> 16);
}

__device__ __forceinline__ unsigned pkbf(float a, float b) {
  return (unsigned)f2bf_rn(a) | ((unsigned)f2bf_rn(b) << 16);
}

__device__ __forceinline__ float blo(unsigned w) { return __uint_as_float(w << 16); }
__device__ __forceinline__ float bhi(unsigned w) { return __uint_as_float(w & 0xFFFF0000u); }

// 4 MACs: packed-bf16 E pair-of-pairs vs f32 q vector, f32 accumulate
__device__ __forceinline__ v4f fma4(u2 e, v4f q, v4f a) {
  a.x = fmaf(blo(e.x), q.x, a.x);
  a.y = fmaf(bhi(e.x), q.y, a.y);
  a.z = fmaf(blo(e.y), q.z, a.z);
  a.w = fmaf(bhi(e.y), q.w, a.w);
  return a;
}

// OR of (sign-adjusted) words: ready iff top bit of result is 0
__device__ __forceinline__ unsigned orsgn(v4f v, unsigned e) {
  return (__float_as_uint(v.x) ^ e) | (__float_as_uint(v.y) ^ e)
       | (__float_as_uint(v.z) ^ e) | (__float_as_uint(v.w) ^ e);
}

// ---------- kernel A: q0 = exp(log_M0 + log_emit[0]) (positive = sign for t=0) ----------
__global__ void init_q(const float* __restrict__ m0, const float* __restrict__ emit,
                       float* __restrict__ q) {
  int i = blockIdx.x * 256 + threadIdx.x;
  q[i] = __expf(m0[i] + emit[i]);
}

// ---------- kernel B: persistent forward recursion (r7 protocol, 512-thread) ----------
// 256 blocks x 512 THREADS (8 waves), 1 block/CU. Block b owns rows
// [16b,16b+16); wave w owns rows [16b+2w, +2). E in 32 named u2 regs
// (packed bf16, 64 VGPR/lane): per-thread GEMV halves vs round 7
// (128 MACs ~600cyc). Protocol byte-identical to round 7: poll full-data
// first (common case 1 pass), sentinel retries, stage raw to LDS double
// buffer, ONE barrier, GEMV, reduce, store WITH drain (r8: drain is
// load-bearing for visibility). Stores are 8B dwordx2 (atomic chunk);
// sign protocol per 8B chunk. Stored sign of step t is s_t =
// ((t>>1)&1)? -1:+1; output scale folds s_t*s_{t-1} (+ odd t, - even t);
// 0xAA poison is negative. Accumulation order per output row identical
// to r7 -> bit-identical result.
// NEW: straggle side-channel — one 64-way bank-conflicted ds_read per
// sentinel retry pass makes SQ_LDS_BANK_CONFLICT a retry counter.
#define K16(X) X(0) X(1) X(2) X(3) X(4) X(5) X(6) X(7) \
               X(8) X(9) X(10) X(11) X(12) X(13) X(14) X(15)

__global__ void __launch_bounds__(512, 1) __attribute__((amdgpu_waves_per_eu(2, 2)))
hmm_fwd(const float* __restrict__ lt, const float* __restrict__ emit,
        float* q, float* out) {
  __shared__ float qs[2][SS];              // 32 KiB (double buffer)
  __shared__ float wsum[4];
  const int b    = blockIdx.x;
  const int tid  = threadIdx.x;
  const int wave = tid >> 6;
  const int lane = tid & 63;
  const int row0 = (b << 4) + (wave << 1);   // 2 rows per wave

  // 32 named packed-bf16 E registers:
  // e{r}_{k} = bf16(exp(log_trans[row0+r][k*256+4l .. +4])), 2x2 packed
#define DECL_E(k) u2 e0_##k, e1_##k;
  K16(DECL_E)
#undef DECL_E

  {
    const float* s0 = lt + (size_t)row0 * SS + (lane << 2);
    const float* s1 = s0 + SS;
#define INIT_E(k) { \
    v4f t0 = *(const v4f*)(s0 + ((k) << 8)); \
    v4f t1 = *(const v4f*)(s1 + ((k) << 8)); \
    e0_##k = (u2){pkbf(__expf(t0.x), __expf(t0.y)), pkbf(__expf(t0.z), __expf(t0.w))}; \
    e1_##k = (u2){pkbf(__expf(t1.x), __expf(t1.y)), pkbf(__expf(t1.z), __expf(t1.w))}; }
    K16(INIT_E)
#undef INIT_E
  }

  for (int t = 1; t <= TT; ++t) {
    // issue emit load early: HBM latency overlaps the poll
    v2f em;
    if (lane == 0) em = *(const v2f*)(emit + (size_t)t * SS + row0);

    // poll q_{t-1}: expected stored-sign of step t-1
    const unsigned e = (unsigned)(((t - 1) >> 1) & 1) << 31;
    {
      const v4f* qsrc4 = (const v4f*)(q + ((t - 1) & 1) * SS);
      v4f va, vb;
      // pass 1: full-data load (common case: ready, zero extra round trip)
      llc_load2(qsrc4 + tid, va, vb);
      unsigned o = orsgn(va, e) | orsgn(vb, e);
      if (o >> 31) {
        // stragglers: 4-dword sentinel spin (word0 of each 8B chunk)
        const float* qw = (const float*)qsrc4;
        const float* p0 = qw + (tid << 2);
        const float* p1 = p0 + 2;
        const float* p2 = p0 + 2048;
        const float* p3 = p0 + 2050;
        for (;;) {
          straggle_tick(lane);   // side-channel: count this pass
          float s0v, s1v, s2v, s3v;
          llc_sent4(p0, p1, p2, p3, s0v, s1v, s2v, s3v);
          unsigned so = (__float_as_uint(s0v) ^ e) | (__float_as_uint(s1v) ^ e)
                      | (__float_as_uint(s2v) ^ e) | (__float_as_uint(s3v) ^ e);
          if (!(so >> 31)) break;
        }
        llc_load2(qsrc4 + tid, va, vb);   // data now LLC-resident
      }
      // stage RAW (sign s_{t-1} kept; folded into output scale)
      v4f* qsb = (v4f*)qs[t & 1];
      qsb[tid]       = va;
      qsb[tid + 512] = vb;
    }
    __syncthreads();   // single barrier per step (double-buffered qs)

    // GEMV: 2 rows per lane from bf16 registers, one v4f of q per k (16 LDS reads)
    v4f a0 = {0.f, 0.f, 0.f, 0.f}, a1 = a0;
    const v4f* qv4 = (const v4f*)qs[t & 1];
#define FMA_K(k) { \
    v4f qv = qv4[((k) << 6) + lane]; \
    a0 = fma4(e0_##k, qv, a0);  a1 = fma4(e1_##k, qv, a1); }
    K16(FMA_K)
#undef FMA_K

    float acc0 = (a0.x + a0.y) + (a0.z + a0.w);
    float acc1 = (a1.x + a1.y) + (a1.z + a1.w);
#pragma unroll
    for (int m = 32; m > 0; m >>= 1) {
      acc0 += __shfl_xor(acc0, m);
      acc1 += __shfl_xor(acc1, m);
    }

    // publish q_t chunk (8B atomic store, WITH drain); scale carries
    // renorm * s_t * s_{t-1}
    if (lane == 0) {
      float scale = ((t & 255) == 0) ? 0x1p-46f : 1.0f;  // exact pow2 renorm
      if (!(t & 1)) scale = -scale;                       // s_t * s_{t-1}
      v2f r;
      r.x = acc0 * (__expf(em.x) * scale);
      r.y = acc1 * (__expf(em.y) * scale);
      llc_store2_drain(q + (t & 1) * SS + row0, r);
    }
  }

  // final reduction: q_T (t=2048) in buffer 0, stored sign positive
  if (b == 0) {
    float s = 0.f;
    if (tid < 256) {
      const v4f* qf4 = (const v4f*)q;
      v4f va, vb, vc, vd;
      for (;;) {
        llc_load4x4(qf4 + tid, va, vb, vc, vd);
        unsigned o = orsgn(va, 0) | orsgn(vb, 0) | orsgn(vc, 0) | orsgn(vd, 0);
        if (!(o >> 31)) break;
      }
      s = va.x + va.y + va.z + va.w + vb.x + vb.y + vb.z + vb.w
        + vc.x + vc.y + vc.z + vc.w + vd.x + vd.y + vd.z + vd.w;
#pragma unroll
      for (int m = 32; m > 0; m >>= 1) s += __shfl_xor(s, m);
      if (lane == 0) wsum[wave] = s;
    }
    __syncthreads();
    if (tid == 0) {
      float tot = wsum[0] + wsum[1] + wsum[2] + wsum[3];
      out[0] = logf(tot) + 368.0f * 0.693147180559945f;   // 8 rescales * 46 * ln2
    }
  }
}

// ---------- launch ----------
extern "C" void kernel_launch(void* const* d_in, const int* in_sizes, int n_in,
                              void* d_out, int out_size, void* d_ws, size_t ws_size,
                              hipStream_t stream) {
  const float* log_M0    = (const float*)d_in[0];
  const float* log_trans = (const float*)d_in[1];
  const float* log_emit  = (const float*)d_in[2];
  // d_in[3] = T (fixed 2048, unused)

  float* q   = (float*)d_ws;     // 2 x 16 KiB (poisoned 0xAA = negative)
  float* out = (float*)d_out;

  hipLaunchKernelGGL(init_q, dim3(SS / 256), dim3(256), 0, stream, log_M0, log_emit, q);
  hipLaunchKernelGGL(hmm_fwd, dim3(256), dim3(512), 0, stream, log_trans, log_emit, q, out);
}